// Round 9
// baseline (656.215 us; speedup 1.0000x reference)
//
#include <hip/hip_runtime.h>
#include <hip/hip_cooperative_groups.h>

namespace cg = cooperative_groups;

// LiftSplatShoot dims
#define B_   8
#define N_   6
#define D_   41
#define FH_  8
#define FW_  22
#define C_   64
#define NPRIME (B_*N_*D_*FH_*FW_)   // 346368 = 1353 * 256 exactly
#define NBLK_PTS 1353
#define NX0  200
#define NX1  200
#define G1Q  4                      // g1 quarters of 50
#define NB2  (B_ * NX0 * G1Q)       // 6400 buckets (b, g0, g1/50)
#define OUTSZ (B_*C_*NX0*NX1)       // 20,480,000 floats
#define CAP  128                    // max entries per gather task (short chains)
#define DIRECT_N 16                 // small-task direct-atomic path (no LDS)
#define MAXTASKS 16384
#define FBLK 1024                   // cooperative grid (must be co-resident)
#define FTHR 256
#define LDS_STRIDE 51               // 64ch x 51 floats = 13056 B (fits in sh[])

// ---------------- numpy-faithful fp32 3x3 inverse (LAPACK sgetrf+sgetri) ----
__device__ void lapack_inv3_f32(const float Ain[9], float Aout[9]) {
    #pragma clang fp contract(off)
    float a[9]; // column-major
    for (int r = 0; r < 3; ++r)
        for (int c = 0; c < 3; ++c)
            a[c*3 + r] = Ain[r*3 + c];
    int ipiv[3];
    for (int j = 0; j < 3; ++j) {
        int p = j;
        float amax = fabsf(a[j*3 + j]);
        for (int i = j + 1; i < 3; ++i) {
            float v = fabsf(a[j*3 + i]);
            if (v > amax) { amax = v; p = i; }
        }
        ipiv[j] = p;
        if (p != j)
            for (int c = 0; c < 3; ++c) { float t = a[c*3+j]; a[c*3+j] = a[c*3+p]; a[c*3+p] = t; }
        float d = 1.0f / a[j*3 + j];
        for (int i = j + 1; i < 3; ++i) a[j*3 + i] = a[j*3 + i] * d;
        for (int jj = j + 1; jj < 3; ++jj) {
            float temp = -a[jj*3 + j];
            for (int ii = j + 1; ii < 3; ++ii)
                a[jj*3 + ii] = a[jj*3 + ii] + a[j*3 + ii] * temp;
        }
    }
    for (int j = 0; j < 3; ++j) {
        float ajj_inv = 1.0f / a[j*3 + j];
        a[j*3 + j] = ajj_inv;
        float AJJ = -ajj_inv;
        for (int jj = 0; jj < j; ++jj) {
            float temp = a[j*3 + jj];
            for (int i = 0; i < jj; ++i)
                a[j*3 + i] = a[j*3 + i] + temp * a[jj*3 + i];
            a[j*3 + jj] = a[j*3 + jj] * a[jj*3 + jj];
        }
        for (int i = 0; i < j; ++i) a[j*3 + i] = a[j*3 + i] * AJJ;
    }
    float work[3];
    for (int j = 2; j >= 0; --j) {
        for (int i = j + 1; i < 3; ++i) { work[i] = a[j*3 + i]; a[j*3 + i] = 0.0f; }
        for (int jj = j + 1; jj < 3; ++jj) {
            float temp = -work[jj];
            for (int i = 0; i < 3; ++i)
                a[j*3 + i] = a[j*3 + i] + temp * a[jj*3 + i];
        }
    }
    for (int j = 2; j >= 0; --j) {
        int p = ipiv[j];
        if (p != j)
            for (int i = 0; i < 3; ++i) { float t = a[j*3+i]; a[j*3+i] = a[p*3+i]; a[p*3+i] = t; }
    }
    for (int r = 0; r < 3; ++r)
        for (int c = 0; c < 3; ++c)
            Aout[r*3 + c] = a[c*3 + r];
}

// Fused pipeline: P0 prep+zero | P1 geom+hist | P2 scan | P3 place | P4 gather
__global__ void __launch_bounds__(FTHR, 4) fused_kernel(
        const float* __restrict__ x_feats,
        const float* __restrict__ rots,
        const float* __restrict__ trans,
        const float* __restrict__ intrins,
        const float* __restrict__ post_rots,
        const float* __restrict__ post_trans,
        float* __restrict__ mats,
        int* __restrict__ counts,
        int* __restrict__ offsets,
        int* __restrict__ cursor,
        int* __restrict__ task_count,
        unsigned int* __restrict__ tasks,
        unsigned int* __restrict__ pcode,
        unsigned int* __restrict__ entries,
        float* __restrict__ out) {
    cg::grid_group grid = cg::this_grid();
    __shared__ int sh[NB2];     // 25.6 KB: hist (P1), cnt/base (P3), acc (P4)
    __shared__ int ts[256];     // scan partials (P2)
    __shared__ int tb[256];
    int t   = threadIdx.x;
    int blk = blockIdx.x;
    int gid = blk * FTHR + t;
    int wave = t >> 6, lane = t & 63;

    // ================= P0: prep (block 0) + zero counts + zero out =========
    if (blk == 0 && t < B_ * N_) {
        #pragma clang fp contract(off)
        float pr[9], ipr[9], K[9], iK[9];
        for (int i = 0; i < 9; ++i) { pr[i] = post_rots[t*9 + i]; K[i] = intrins[t*9 + i]; }
        lapack_inv3_f32(pr, ipr);
        lapack_inv3_f32(K, iK);
        float* m = mats + t * 24;
        for (int i = 0; i < 9; ++i) m[i] = ipr[i];
        for (int i = 0; i < 3; ++i)
            for (int k = 0; k < 3; ++k) {
                float s = rots[t*9 + i*3 + 0] * iK[0*3 + k];
                s = s + rots[t*9 + i*3 + 1] * iK[1*3 + k];
                s = s + rots[t*9 + i*3 + 2] * iK[2*3 + k];
                m[9 + i*3 + k] = s;
            }
        for (int i = 0; i < 3; ++i) {
            m[18 + i] = post_trans[t*3 + i];
            m[21 + i] = trans[t*3 + i];
        }
    }
    for (int i = gid; i < NB2; i += FBLK * FTHR) counts[i] = 0;
    {   // zero output grid (harness poisons it with 0xAA every launch)
        float4* out4 = (float4*)out;
        const int TOT4 = OUTSZ / 4;
        float4 z4 = make_float4(0.f, 0.f, 0.f, 0.f);
        for (int i = gid; i < TOT4; i += FBLK * FTHR) out4[i] = z4;
    }
    grid.sync();

    // ================= P1: geom + block-local histogram =====================
    for (int vb = blk; vb < NBLK_PTS; vb += FBLK) {
        #pragma clang fp contract(off)
        for (int i = t; i < NB2; i += FTHR) sh[i] = 0;
        __syncthreads();

        int p  = vb * FTHR + t;
        int w  = p % FW_;
        int h  = (p / FW_) % FH_;
        int d  = (p / (FW_ * FH_)) % D_;
        int bn = p / (FW_ * FH_ * D_);
        int b  = bn / N_;
        const float* m = mats + bn * 24;

        float xs = (w == FW_ - 1) ? 351.0f : (float)((double)w * (351.0 / 21.0));
        float ys = (h == FH_ - 1) ? 127.0f : (float)((double)h * (127.0 / 7.0));
        float ds = 4.0f + (float)d;

        float px = xs - m[18], py = ys - m[19], pz = ds - m[20];
        float qx = m[0]*px;  qx = qx + m[1]*py;  qx = qx + m[2]*pz;
        float qy = m[3]*px;  qy = qy + m[4]*py;  qy = qy + m[5]*pz;
        float qz = m[6]*px;  qz = qz + m[7]*py;  qz = qz + m[8]*pz;

        float ux = qx * qz, uy = qy * qz, uz = qz;

        float gx = m[9]*ux;   gx = gx + m[10]*uy;  gx = gx + m[11]*uz;  gx = gx + m[21];
        float gy = m[12]*ux;  gy = gy + m[13]*uy;  gy = gy + m[14]*uz;  gy = gy + m[22];
        float gz = m[15]*ux;  gz = gz + m[16]*uy;  gz = gz + m[17]*uz;  gz = gz + m[23];

        float cx = (gx - (-50.0f)) / 0.5f;
        float cy = (gy - (-50.0f)) / 0.5f;
        float cz = (gz - (-10.0f)) / 20.0f;
        int g0 = (int)cx;
        int g1 = (int)cy;
        int g2 = (int)cz;

        bool kept = (g0 >= 0) && (g0 < NX0) && (g1 >= 0) && (g1 < NX1) && (g2 == 0);
        if (kept) {
            int g1q = g1 / 50;
            int g1r = g1 - g1q * 50;
            int bk  = (b * NX0 + g0) * G1Q + g1q;
            pcode[p] = ((unsigned int)bk << 6) | (unsigned int)g1r;
            atomicAdd(&sh[bk], 1);
        } else {
            pcode[p] = 0xFFFFFFFFu;
        }
        __syncthreads();
        for (int i = t; i < NB2; i += FTHR) {
            int hv = sh[i];
            if (hv) atomicAdd(&counts[i], hv);
        }
        __syncthreads();   // protect sh before next virtual block
    }
    grid.sync();

    // ================= P2: scan + task emit (block 0 only) ==================
    if (blk == 0) {
        const int PER = NB2 / FTHR; // 25
        int base = t * PER;
        int mysum = 0, mytasks = 0;
        for (int j = 0; j < PER; ++j) {
            int c = counts[base + j];
            mysum += c;
            if (c > 0) mytasks += (c + CAP - 1) / CAP;
        }
        ts[t] = mysum;
        tb[t] = mytasks;
        __syncthreads();
        for (int off = 1; off < FTHR; off <<= 1) {
            int v  = (t >= off) ? ts[t - off] : 0;
            int tv = (t >= off) ? tb[t - off] : 0;
            __syncthreads();
            ts[t] += v;
            tb[t] += tv;
            __syncthreads();
        }
        int run  = (t > 0) ? ts[t - 1] : 0;
        int tpos = (t > 0) ? tb[t - 1] : 0;
        for (int j = 0; j < PER; ++j) {
            int c = counts[base + j];
            offsets[base + j] = run;
            cursor[base + j]  = run;
            run += c;
            if (c > 0) {
                int nch = (c + CAP - 1) / CAP;
                unsigned int sole = (nch == 1) ? (1u << 31) : 0u;
                for (int k = 0; k < nch; ++k)
                    tasks[tpos++] = sole | ((unsigned int)(base + j) << 12) | (unsigned int)k;
            }
        }
        if (t == FTHR - 1) {
            offsets[NB2] = run;
            task_count[0] = tb[FTHR - 1];
        }
    }
    grid.sync();

    // ================= P3: place (compact into bucket segments) =============
    for (int vb = blk; vb < NBLK_PTS; vb += FBLK) {
        for (int i = t; i < NB2; i += FTHR) sh[i] = 0;
        __syncthreads();
        int p = vb * FTHR + t;
        unsigned int code = pcode[p];
        bool kept = (code != 0xFFFFFFFFu);
        int bk = (int)(code >> 6);
        int lr = 0;
        if (kept) lr = atomicAdd(&sh[bk], 1);
        __syncthreads();
        for (int i = t; i < NB2; i += FTHR) {
            int c = sh[i];
            if (c) sh[i] = atomicAdd(&cursor[i], c);   // overwrite with global base
        }
        __syncthreads();
        if (kept)
            entries[sh[bk] + lr] = ((code & 63u) << 19) | (unsigned int)p;
        __syncthreads();   // protect sh before next virtual block
    }
    grid.sync();

    // ================= P4: gather over size-capped tasks ====================
    float* acc = (float*)sh;   // 13056 B of the 25.6 KB block
    int ntask = task_count[0];
    for (int tid = blk; tid < ntask; tid += FBLK) {
        unsigned int task = tasks[tid];
        int sole = (int)(task >> 31);
        int bk   = (int)((task >> 12) & 0x1FFFu);
        int ch   = (int)(task & 0xFFFu);
        int s = offsets[bk] + ch * CAP;
        int e = offsets[bk + 1];
        if (e > s + CAP) e = s + CAP;
        int n = e - s;

        int b   = bk / (NX0 * G1Q);
        int rem = bk % (NX0 * G1Q);
        int g0  = rem / G1Q, g1q = rem % G1Q;
        size_t obase = (size_t)b * (C_ * NX0 * NX1) + (size_t)g0 * NX1 + g1q * 50;

        if (n <= DIRECT_N) {
            for (int i = wave; i < n; i += 4) {
                unsigned int v = entries[s + i];
                float f = x_feats[(size_t)(v & 0x7FFFFu) * C_ + lane];
                unsafeAtomicAdd(&out[obase + (size_t)lane * (NX0 * NX1) + (int)(v >> 19)], f);
            }
            continue;
        }

        for (int i = t; i < C_ * LDS_STRIDE; i += FTHR) acc[i] = 0.0f;
        __syncthreads();

        // full 32-entry sweeps: 4 waves x 8-entry ILP
        int nfull = (n >> 5) << 5;
        for (int sbase = 0; sbase < nfull; sbase += 32) {
            int i0 = s + sbase + wave * 8;
            unsigned int v0 = entries[i0],     v1 = entries[i0 + 1];
            unsigned int v2 = entries[i0 + 2], v3 = entries[i0 + 3];
            unsigned int v4 = entries[i0 + 4], v5 = entries[i0 + 5];
            unsigned int v6 = entries[i0 + 6], v7 = entries[i0 + 7];
            float f0 = x_feats[(size_t)(v0 & 0x7FFFFu) * C_ + lane];
            float f1 = x_feats[(size_t)(v1 & 0x7FFFFu) * C_ + lane];
            float f2 = x_feats[(size_t)(v2 & 0x7FFFFu) * C_ + lane];
            float f3 = x_feats[(size_t)(v3 & 0x7FFFFu) * C_ + lane];
            float f4 = x_feats[(size_t)(v4 & 0x7FFFFu) * C_ + lane];
            float f5 = x_feats[(size_t)(v5 & 0x7FFFFu) * C_ + lane];
            float f6 = x_feats[(size_t)(v6 & 0x7FFFFu) * C_ + lane];
            float f7 = x_feats[(size_t)(v7 & 0x7FFFFu) * C_ + lane];
            int lb = lane * LDS_STRIDE;
            atomicAdd(&acc[lb + (int)(v0 >> 19)], f0);
            atomicAdd(&acc[lb + (int)(v1 >> 19)], f1);
            atomicAdd(&acc[lb + (int)(v2 >> 19)], f2);
            atomicAdd(&acc[lb + (int)(v3 >> 19)], f3);
            atomicAdd(&acc[lb + (int)(v4 >> 19)], f4);
            atomicAdd(&acc[lb + (int)(v5 >> 19)], f5);
            atomicAdd(&acc[lb + (int)(v6 >> 19)], f6);
            atomicAdd(&acc[lb + (int)(v7 >> 19)], f7);
        }
        for (int i = nfull + wave; i < n; i += 4) {
            unsigned int v = entries[s + i];
            float f = x_feats[(size_t)(v & 0x7FFFFu) * C_ + lane];
            atomicAdd(&acc[lane * LDS_STRIDE + (int)(v >> 19)], f);
        }
        __syncthreads();

        for (int k = t; k < C_ * 50; k += FTHR) {
            int c = k / 50, r = k - c * 50;
            float val = acc[c * LDS_STRIDE + r];
            if (val != 0.0f) {
                float* dst = &out[obase + (size_t)c * (NX0 * NX1) + r];
                if (sole) *dst = val;
                else unsafeAtomicAdd(dst, val);
            }
        }
        __syncthreads();   // protect acc before next task's init
    }
}

extern "C" void kernel_launch(void* const* d_in, const int* in_sizes, int n_in,
                              void* d_out, int out_size, void* d_ws, size_t ws_size,
                              hipStream_t stream) {
    const float* x_feats    = (const float*)d_in[0];
    const float* rots       = (const float*)d_in[1];
    const float* trans      = (const float*)d_in[2];
    const float* intrins    = (const float*)d_in[3];
    const float* post_rots  = (const float*)d_in[4];
    const float* post_trans = (const float*)d_in[5];
    float* out = (float*)d_out;

    // ws layout (~3 MB)
    char* w = (char*)d_ws;
    float*        mats       = (float*)w;         w += 48 * 24 * sizeof(float);
    int*          counts     = (int*)w;           w += NB2 * sizeof(int);
    int*          offsets    = (int*)w;           w += (NB2 + 1) * sizeof(int);
    int*          cursor     = (int*)w;           w += NB2 * sizeof(int);
    int*          task_count = (int*)w;           w += 4 * sizeof(int);
    unsigned int* tasks      = (unsigned int*)w;  w += MAXTASKS * sizeof(unsigned int);
    unsigned int* pcode      = (unsigned int*)w;  w += NPRIME * sizeof(unsigned int);
    unsigned int* entries    = (unsigned int*)w;  w += NPRIME * sizeof(unsigned int);

    void* args[] = {
        (void*)&x_feats, (void*)&rots, (void*)&trans, (void*)&intrins,
        (void*)&post_rots, (void*)&post_trans,
        (void*)&mats, (void*)&counts, (void*)&offsets, (void*)&cursor,
        (void*)&task_count, (void*)&tasks, (void*)&pcode, (void*)&entries,
        (void*)&out
    };
    hipLaunchCooperativeKernel((void*)fused_kernel, dim3(FBLK), dim3(FTHR),
                               args, 0, stream);
}

// Round 10
// 230.710 us; speedup vs baseline: 2.8443x; 2.8443x over previous
//
#include <hip/hip_runtime.h>

// LiftSplatShoot dims
#define B_   8
#define N_   6
#define D_   41
#define FH_  8
#define FW_  22
#define C_   64
#define PPC  (D_*FH_*FW_)           // 7216 points per (b,n)
#define NPRIME (B_*N_*D_*FH_*FW_)   // 346368 = 1353 * 256 exactly
#define NBLK_PTS 1353
#define NX0  200
#define NX1  200
#define G1Q  4                      // g1 quarters of 50
#define NB2  (B_ * NX0 * G1Q)       // 6400 buckets (b, g0, g1/50)
#define OUTSZ (B_*C_*NX0*NX1)       // 20,480,000 floats
#define CAP  128                    // max entries per sole bucket / chunk
#define MAXTASKS 8192
#define MAXMC 1024                  // multi-chunk bucket list capacity
#define GATHER_BLOCKS 1024
#define REGION (C_ * 50)            // 3200 floats per bucket region

// ---------------- numpy-faithful fp32 3x3 inverse (LAPACK sgetrf+sgetri) ----
__device__ void lapack_inv3_f32(const float Ain[9], float Aout[9]) {
    #pragma clang fp contract(off)
    float a[9]; // column-major
    for (int r = 0; r < 3; ++r)
        for (int c = 0; c < 3; ++c)
            a[c*3 + r] = Ain[r*3 + c];
    int ipiv[3];
    for (int j = 0; j < 3; ++j) {
        int p = j;
        float amax = fabsf(a[j*3 + j]);
        for (int i = j + 1; i < 3; ++i) {
            float v = fabsf(a[j*3 + i]);
            if (v > amax) { amax = v; p = i; }
        }
        ipiv[j] = p;
        if (p != j)
            for (int c = 0; c < 3; ++c) { float t = a[c*3+j]; a[c*3+j] = a[c*3+p]; a[c*3+p] = t; }
        float d = 1.0f / a[j*3 + j];
        for (int i = j + 1; i < 3; ++i) a[j*3 + i] = a[j*3 + i] * d;
        for (int jj = j + 1; jj < 3; ++jj) {
            float temp = -a[jj*3 + j];
            for (int ii = j + 1; ii < 3; ++ii)
                a[jj*3 + ii] = a[jj*3 + ii] + a[j*3 + ii] * temp;
        }
    }
    for (int j = 0; j < 3; ++j) {
        float ajj_inv = 1.0f / a[j*3 + j];
        a[j*3 + j] = ajj_inv;
        float AJJ = -ajj_inv;
        for (int jj = 0; jj < j; ++jj) {
            float temp = a[j*3 + jj];
            for (int i = 0; i < jj; ++i)
                a[j*3 + i] = a[j*3 + i] + temp * a[jj*3 + i];
            a[j*3 + jj] = a[j*3 + jj] * a[jj*3 + jj];
        }
        for (int i = 0; i < j; ++i) a[j*3 + i] = a[j*3 + i] * AJJ;
    }
    float work[3];
    for (int j = 2; j >= 0; --j) {
        for (int i = j + 1; i < 3; ++i) { work[i] = a[j*3 + i]; a[j*3 + i] = 0.0f; }
        for (int jj = j + 1; jj < 3; ++jj) {
            float temp = -work[jj];
            for (int i = 0; i < 3; ++i)
                a[j*3 + i] = a[j*3 + i] + temp * a[jj*3 + i];
        }
    }
    for (int j = 2; j >= 0; --j) {
        int p = ipiv[j];
        if (p != j)
            for (int i = 0; i < 3; ++i) { float t = a[j*3+i]; a[j*3+i] = a[p*3+i]; a[p*3+i] = t; }
    }
    for (int r = 0; r < 3; ++r)
        for (int c = 0; c < 3; ++c)
            Aout[r*3 + c] = a[c*3 + r];
}

// Compute [invPR 0..8 | combine 9..17 | post_trans 18..20 | trans 21..23] for bn.
__device__ void make_mats(int bn,
                          const float* __restrict__ rots,
                          const float* __restrict__ trans,
                          const float* __restrict__ intrins,
                          const float* __restrict__ post_rots,
                          const float* __restrict__ post_trans,
                          float* m) {
    #pragma clang fp contract(off)
    float pr[9], ipr[9], K[9], iK[9];
    for (int i = 0; i < 9; ++i) { pr[i] = post_rots[bn*9 + i]; K[i] = intrins[bn*9 + i]; }
    lapack_inv3_f32(pr, ipr);
    lapack_inv3_f32(K, iK);
    for (int i = 0; i < 9; ++i) m[i] = ipr[i];
    for (int i = 0; i < 3; ++i)
        for (int k = 0; k < 3; ++k) {
            float s = rots[bn*9 + i*3 + 0] * iK[0*3 + k];
            s = s + rots[bn*9 + i*3 + 1] * iK[1*3 + k];
            s = s + rots[bn*9 + i*3 + 2] * iK[2*3 + k];
            m[9 + i*3 + k] = s;
        }
    for (int i = 0; i < 3; ++i) {
        m[18 + i] = post_trans[bn*3 + i];
        m[21 + i] = trans[bn*3 + i];
    }
}

// Zero counts + task_count + mc_count (contiguous NB2+4 ints).
__global__ void init_kernel(int* __restrict__ counts) {
    int i = blockIdx.x * blockDim.x + threadIdx.x;
    if (i < NB2 + 4) counts[i] = 0;
}

// One thread per point (grid exact): inline per-block camera matrices (1-2 bn),
// fp32 numpy-faithful geometry -> pcode=(bk<<6)|g1r; LDS histogram flush.
__global__ void __launch_bounds__(256) geom_kernel(
        const float* __restrict__ rots,
        const float* __restrict__ trans,
        const float* __restrict__ intrins,
        const float* __restrict__ post_rots,
        const float* __restrict__ post_trans,
        unsigned int* __restrict__ pcode,
        int* __restrict__ counts) {
    #pragma clang fp contract(off)
    __shared__ int hist[NB2];        // 25.6 KB
    __shared__ float smat[2][24];
    int t = threadIdx.x;
    int p = blockIdx.x * 256 + t;
    for (int i = t; i < NB2; i += 256) hist[i] = 0;

    int p0  = blockIdx.x * 256;
    int bn0 = p0 / PPC;
    int bn1 = (p0 + 255) / PPC;      // at most bn0+1
    if (t < 2) {
        int bnv = (t == 0) ? bn0 : bn1;
        make_mats(bnv, rots, trans, intrins, post_rots, post_trans, smat[t]);
    }
    __syncthreads();

    int w  = p % FW_;
    int h  = (p / FW_) % FH_;
    int d  = (p / (FW_ * FH_)) % D_;
    int bn = p / PPC;
    int b  = bn / N_;
    const float* m = smat[(bn == bn0) ? 0 : 1];

    float xs = (w == FW_ - 1) ? 351.0f : (float)((double)w * (351.0 / 21.0));
    float ys = (h == FH_ - 1) ? 127.0f : (float)((double)h * (127.0 / 7.0));
    float ds = 4.0f + (float)d;

    float px = xs - m[18], py = ys - m[19], pz = ds - m[20];
    float qx = m[0]*px;  qx = qx + m[1]*py;  qx = qx + m[2]*pz;
    float qy = m[3]*px;  qy = qy + m[4]*py;  qy = qy + m[5]*pz;
    float qz = m[6]*px;  qz = qz + m[7]*py;  qz = qz + m[8]*pz;

    float ux = qx * qz, uy = qy * qz, uz = qz;

    float gx = m[9]*ux;   gx = gx + m[10]*uy;  gx = gx + m[11]*uz;  gx = gx + m[21];
    float gy = m[12]*ux;  gy = gy + m[13]*uy;  gy = gy + m[14]*uz;  gy = gy + m[22];
    float gz = m[15]*ux;  gz = gz + m[16]*uy;  gz = gz + m[17]*uz;  gz = gz + m[23];

    float cx = (gx - (-50.0f)) / 0.5f;
    float cy = (gy - (-50.0f)) / 0.5f;
    float cz = (gz - (-10.0f)) / 20.0f;
    int g0 = (int)cx;
    int g1 = (int)cy;
    int g2 = (int)cz;

    bool kept = (g0 >= 0) && (g0 < NX0) && (g1 >= 0) && (g1 < NX1) && (g2 == 0);
    if (kept) {
        int g1q = g1 / 50;
        int g1r = g1 - g1q * 50;
        int bk  = (b * NX0 + g0) * G1Q + g1q;
        pcode[p] = ((unsigned int)bk << 6) | (unsigned int)g1r;
        atomicAdd(&hist[bk], 1);
    } else {
        pcode[p] = 0xFFFFFFFFu;
    }
    __syncthreads();
    for (int i = t; i < NB2; i += 256) {
        int hv = hist[i];
        if (hv) atomicAdd(&counts[i], hv);
    }
}

// Single-block: scan counts -> offsets/cursor; emit one task per bucket
// (sole, covers c<=CAP including c==0) or nch chunk tasks + mc-zero entry.
// Task: bit31=sole, bits[12:25)=bucket, bits[0:12)=chunk.
__global__ void scan_kernel(const int* __restrict__ counts,
                            int* __restrict__ offsets,
                            int* __restrict__ cursor,
                            unsigned int* __restrict__ tasks,
                            int* __restrict__ task_count,
                            int* __restrict__ mc_count,
                            int* __restrict__ mcbuckets) {
    __shared__ int ts[256];
    __shared__ int tb[256];
    int t = threadIdx.x;
    const int PER = NB2 / 256; // 25
    int base = t * PER;
    int mysum = 0, mytasks = 0;
    for (int j = 0; j < PER; ++j) {
        int c = counts[base + j];
        mysum += c;
        mytasks += (c <= CAP) ? 1 : (c + CAP - 1) / CAP;
    }
    ts[t] = mysum;
    tb[t] = mytasks;
    __syncthreads();
    for (int off = 1; off < 256; off <<= 1) {
        int v  = (t >= off) ? ts[t - off] : 0;
        int tv = (t >= off) ? tb[t - off] : 0;
        __syncthreads();
        ts[t] += v;
        tb[t] += tv;
        __syncthreads();
    }
    int run  = (t > 0) ? ts[t - 1] : 0;
    int tpos = (t > 0) ? tb[t - 1] : 0;
    for (int j = 0; j < PER; ++j) {
        int bk = base + j;
        int c = counts[bk];
        offsets[bk] = run;
        cursor[bk]  = run;
        run += c;
        if (c <= CAP) {
            tasks[tpos++] = (1u << 31) | ((unsigned int)bk << 12);
        } else {
            int nch = (c + CAP - 1) / CAP;
            for (int k = 0; k < nch; ++k)
                tasks[tpos++] = ((unsigned int)bk << 12) | (unsigned int)k;
            int mi = atomicAdd(mc_count, 1);
            if (mi < MAXMC) mcbuckets[mi] = bk;
        }
    }
    if (t == 255) {
        offsets[NB2] = run;
        task_count[0] = tb[255];
    }
}

// Compact kept points (block-aggregated reservation) + pre-zero the few
// multi-chunk bucket regions (so gather's chunk flush can atomic-add).
__global__ void __launch_bounds__(256) place_kernel(
        const unsigned int* __restrict__ pcode,
        int* __restrict__ cursor,
        unsigned int* __restrict__ entries,
        const int* __restrict__ mc_count,
        const int* __restrict__ mcbuckets,
        float* __restrict__ out) {
    __shared__ int cnt[NB2];   // 25.6 KB (counts, then global bases)
    int t = threadIdx.x;
    int p = blockIdx.x * 256 + t;
    for (int i = t; i < NB2; i += 256) cnt[i] = 0;
    __syncthreads();
    unsigned int code = pcode[p];
    bool kept = (code != 0xFFFFFFFFu);
    int bk = (int)(code >> 6);
    int lr = 0;
    if (kept) lr = atomicAdd(&cnt[bk], 1);
    __syncthreads();
    for (int i = t; i < NB2; i += 256) {
        int c = cnt[i];
        if (c) cnt[i] = atomicAdd(&cursor[i], c);   // overwrite with global base
    }
    __syncthreads();
    if (kept)
        entries[cnt[bk] + lr] = ((code & 63u) << 19) | (unsigned int)p;

    // pre-zero multi-chunk regions (few hundred max)
    int nmc = mc_count[0];
    if (nmc > MAXMC) nmc = MAXMC;
    for (int i = blockIdx.x; i < nmc; i += NBLK_PTS) {
        int mbk = mcbuckets[i];
        int b   = mbk / (NX0 * G1Q);
        int rem = mbk % (NX0 * G1Q);
        int g0  = rem / G1Q, g1q = rem % G1Q;
        size_t obase = (size_t)b * (C_ * NX0 * NX1) + (size_t)g0 * NX1 + g1q * 50;
        for (int k = t; k < REGION; k += 256) {
            int c = k / 50, r = k - c * 50;
            out[obase + (size_t)c * (NX0 * NX1) + r] = 0.0f;
        }
    }
}

// Gather: sole writer of the output grid. One task per bucket region:
//  - empty sole: stream zeros
//  - sole (c<=CAP): LDS accumulate, plain-store full region (incl zeros)
//  - chunk: LDS accumulate, atomic-add nonzero cells (region pre-zeroed)
#define LDS_STRIDE 51
__global__ void __launch_bounds__(512) gather_kernel(
        const float* __restrict__ x_feats,
        const unsigned int* __restrict__ entries,
        const int* __restrict__ offsets,
        const unsigned int* __restrict__ tasks,
        const int* __restrict__ task_count,
        float* __restrict__ out) {
    __shared__ float acc[C_ * LDS_STRIDE]; // 13056 B
    int ntask = task_count[0];
    int t = threadIdx.x, wave = t >> 6, lane = t & 63;

    for (int tid = blockIdx.x; tid < ntask; tid += GATHER_BLOCKS) {
        unsigned int task = tasks[tid];
        int sole = (int)(task >> 31);
        int bk   = (int)((task >> 12) & 0x1FFFu);
        int ch   = (int)(task & 0xFFFu);
        int s = offsets[bk] + ch * CAP;
        int e = offsets[bk + 1];
        if (e > s + CAP) e = s + CAP;
        int n = e - s;

        int b   = bk / (NX0 * G1Q);
        int rem = bk % (NX0 * G1Q);
        int g0  = rem / G1Q, g1q = rem % G1Q;
        size_t obase = (size_t)b * (C_ * NX0 * NX1) + (size_t)g0 * NX1 + g1q * 50;

        if (n == 0) {   // empty bucket: stream zeros (sole by construction)
            for (int k = t; k < REGION; k += 512) {
                int c = k / 50, r = k - c * 50;
                out[obase + (size_t)c * (NX0 * NX1) + r] = 0.0f;
            }
            continue;
        }

        for (int i = t; i < C_ * LDS_STRIDE; i += 512) acc[i] = 0.0f;
        __syncthreads();

        // full 64-entry sweeps: 8 waves x 8-entry ILP
        int nfull = (n >> 6) << 6;
        for (int sbase = 0; sbase < nfull; sbase += 64) {
            int i0 = s + sbase + wave * 8;
            unsigned int v0 = entries[i0],     v1 = entries[i0 + 1];
            unsigned int v2 = entries[i0 + 2], v3 = entries[i0 + 3];
            unsigned int v4 = entries[i0 + 4], v5 = entries[i0 + 5];
            unsigned int v6 = entries[i0 + 6], v7 = entries[i0 + 7];
            float f0 = x_feats[(size_t)(v0 & 0x7FFFFu) * C_ + lane];
            float f1 = x_feats[(size_t)(v1 & 0x7FFFFu) * C_ + lane];
            float f2 = x_feats[(size_t)(v2 & 0x7FFFFu) * C_ + lane];
            float f3 = x_feats[(size_t)(v3 & 0x7FFFFu) * C_ + lane];
            float f4 = x_feats[(size_t)(v4 & 0x7FFFFu) * C_ + lane];
            float f5 = x_feats[(size_t)(v5 & 0x7FFFFu) * C_ + lane];
            float f6 = x_feats[(size_t)(v6 & 0x7FFFFu) * C_ + lane];
            float f7 = x_feats[(size_t)(v7 & 0x7FFFFu) * C_ + lane];
            int lb = lane * LDS_STRIDE;
            atomicAdd(&acc[lb + (int)(v0 >> 19)], f0);
            atomicAdd(&acc[lb + (int)(v1 >> 19)], f1);
            atomicAdd(&acc[lb + (int)(v2 >> 19)], f2);
            atomicAdd(&acc[lb + (int)(v3 >> 19)], f3);
            atomicAdd(&acc[lb + (int)(v4 >> 19)], f4);
            atomicAdd(&acc[lb + (int)(v5 >> 19)], f5);
            atomicAdd(&acc[lb + (int)(v6 >> 19)], f6);
            atomicAdd(&acc[lb + (int)(v7 >> 19)], f7);
        }
        for (int i = nfull + wave; i < n; i += 8) {
            unsigned int v = entries[s + i];
            float f = x_feats[(size_t)(v & 0x7FFFFu) * C_ + lane];
            atomicAdd(&acc[lane * LDS_STRIDE + (int)(v >> 19)], f);
        }
        __syncthreads();

        if (sole) {
            // plain-store full region (this task is the only writer)
            for (int k = t; k < REGION; k += 512) {
                int c = k / 50, r = k - c * 50;
                out[obase + (size_t)c * (NX0 * NX1) + r] = acc[c * LDS_STRIDE + r];
            }
        } else {
            // chunk of a hot bucket: region pre-zeroed, add nonzero cells
            for (int k = t; k < REGION; k += 512) {
                int c = k / 50, r = k - c * 50;
                float val = acc[c * LDS_STRIDE + r];
                if (val != 0.0f)
                    unsafeAtomicAdd(&out[obase + (size_t)c * (NX0 * NX1) + r], val);
            }
        }
        __syncthreads();   // protect acc before next task's init
    }
}

extern "C" void kernel_launch(void* const* d_in, const int* in_sizes, int n_in,
                              void* d_out, int out_size, void* d_ws, size_t ws_size,
                              hipStream_t stream) {
    const float* x_feats    = (const float*)d_in[0];
    const float* rots       = (const float*)d_in[1];
    const float* trans      = (const float*)d_in[2];
    const float* intrins    = (const float*)d_in[3];
    const float* post_rots  = (const float*)d_in[4];
    const float* post_trans = (const float*)d_in[5];
    float* out = (float*)d_out;

    // ws layout (~3 MB). counts, task_count, mc_count contiguous for init.
    char* w = (char*)d_ws;
    int*          counts     = (int*)w;           w += NB2 * sizeof(int);
    int*          task_count = (int*)w;           w += sizeof(int);
    int*          mc_count   = (int*)w;           w += sizeof(int);
    w += 2 * sizeof(int);  // pad
    int*          offsets    = (int*)w;           w += (NB2 + 1) * sizeof(int);
    int*          cursor     = (int*)w;           w += NB2 * sizeof(int);
    int*          mcbuckets  = (int*)w;           w += MAXMC * sizeof(int);
    unsigned int* tasks      = (unsigned int*)w;  w += MAXTASKS * sizeof(unsigned int);
    unsigned int* pcode      = (unsigned int*)w;  w += NPRIME * sizeof(unsigned int);
    unsigned int* entries    = (unsigned int*)w;  w += NPRIME * sizeof(unsigned int);

    init_kernel<<<(NB2 + 4 + 255) / 256, 256, 0, stream>>>(counts);
    geom_kernel<<<NBLK_PTS, 256, 0, stream>>>(rots, trans, intrins, post_rots,
                                              post_trans, pcode, counts);
    scan_kernel<<<1, 256, 0, stream>>>(counts, offsets, cursor, tasks,
                                       task_count, mc_count, mcbuckets);
    place_kernel<<<NBLK_PTS, 256, 0, stream>>>(pcode, cursor, entries,
                                               mc_count, mcbuckets, out);
    gather_kernel<<<GATHER_BLOCKS, 512, 0, stream>>>(x_feats, entries, offsets,
                                                     tasks, task_count, out);
}